// Round 4
// baseline (1381.574 us; speedup 1.0000x reference)
//
#include <hip/hip_runtime.h>
#include <hip/hip_bf16.h>

// Problem constants
#define Bb   32
#define Cc   3
#define Hh   32
#define Ww   32
#define HCC  128
#define G4   512          // 4*HC
#define SW   63           // W+H-1
#define DD   94           // H+SW-1
#define NSEQ (Bb*DD*2)    // 6016

// ws layout (floats):
//   [0)            : WT[4][128][512]  (m: 0=fwd_Wi,1=fwd_Wh,2=bwd_Wi,3=bwd_Wh), WT[m][k][j] = W[j][k]
//   [4*65536)      : comb[B][32][32][256]  (channels: 0..127 fwd h, 128..255 bwd h)
#define WT_FLOATS   (4*65536)
#define COMB_FLOATS (Bb*Hh*Ww*256)

__device__ __forceinline__ float sigmoid_f(float v) {
    return 1.0f / (1.0f + __expf(-v));
}
__device__ __forceinline__ float tanh_f(float v) {
    // stable: large +v -> e=inf -> 1; large -v -> e=0 -> -1
    float e = __expf(2.0f * v);
    return 1.0f - 2.0f / (e + 1.0f);
}

__global__ void transpose_w(const float* __restrict__ fwi, const float* __restrict__ fwh,
                            const float* __restrict__ bwi, const float* __restrict__ bwh,
                            float* __restrict__ wt) {
    int m = blockIdx.y;
    const float* src = (m == 0) ? fwi : (m == 1) ? fwh : (m == 2) ? bwi : bwh;
    int idx = blockIdx.x * 256 + threadIdx.x;   // 0..65535 ; idx = j*128 + k
    int j = idx >> 7;
    int k = idx & 127;
    wt[m * 65536 + k * 512 + j] = src[idx];
}

__global__ __launch_bounds__(512, 2) void lstm_diag(
    const float* __restrict__ x,      // (32,3,32,32)
    const float* __restrict__ ipw,    // (128,3)
    const float* __restrict__ ipb,    // (128)
    const float* __restrict__ fwd_b,  // (512)
    const float* __restrict__ bwd_b,  // (512)
    const float* __restrict__ wt,     // [4][128][512]
    float* __restrict__ comb)         // [32][32][32][256]
{
    __shared__ __align__(16) float xp[32 * 128];   // per-step input projections
    __shared__ __align__(16) float hbuf[128];      // current hidden state
    __shared__ __align__(16) float gates[512];     // gate pre-activations

    const int tid = threadIdx.x;
    const int seq = blockIdx.x;
    const int dir = seq & 1;
    const int rest = seq >> 1;
    const int b = rest / DD;
    const int d = rest - b * DD;

    const int r0   = max(0, d - (SW - 1));
    const int rend = min(Hh - 1, d);
    const int len  = rend - r0 + 1;

    // ---- stage 0: per-cell input projection xp[s][k] (0 for skew-padding cells) ----
    const float inv255 = 1.0f / 255.0f;
    for (int idx = tid; idx < len * 128; idx += 512) {
        int s = idx >> 7;
        int k = idx & 127;
        int row = r0 + s;
        int w = d - 2 * row;          // unskewed column
        float v = 0.0f;
        if ((unsigned)w < 32u) {
            float x0 = x[((b * 3 + 0) * 32 + row) * 32 + w];
            float x1 = x[((b * 3 + 1) * 32 + row) * 32 + w];
            float x2 = x[((b * 3 + 2) * 32 + row) * 32 + w];
            v = ipb[k] + inv255 * (x0 * ipw[k * 3 + 0] + x1 * ipw[k * 3 + 1] + x2 * ipw[k * 3 + 2]);
        }
        xp[idx] = v;
    }
    __syncthreads();

    // ---- stage 1: input gates greg[t] = b[tid] + Wi[tid,:] . xp[s(t),:] ----
    // greg index t is the TIME index (static); the direction reversal is applied
    // on the xp READ side (runtime LDS index is fine; runtime register index is not).
    float wreg[128];
    {
        const float* wtm = wt + (dir * 2 + 0) * 65536;   // Wi^T for this dir
        #pragma unroll
        for (int k = 0; k < 128; k++) wreg[k] = wtm[k * 512 + tid];
    }
    const float bias = (dir ? bwd_b : fwd_b)[tid];

    float greg[32];
    #pragma unroll
    for (int t = 0; t < 32; t++) {
        if (t < len) {
            int s = dir ? (len - 1 - t) : t;
            const float* xs = xp + s * 128;
            float acc = bias;
            #pragma unroll
            for (int k = 0; k < 128; k += 4) {
                float4 v = *(const float4*)(xs + k);
                acc += wreg[k] * v.x + wreg[k + 1] * v.y + wreg[k + 2] * v.z + wreg[k + 3] * v.w;
            }
            greg[t] = acc;
        }
    }

    // ---- stage 2: recurrence; Wh row tid in registers ----
    {
        const float* wtm = wt + (dir * 2 + 1) * 65536;   // Wh^T for this dir
        #pragma unroll
        for (int k = 0; k < 128; k++) wreg[k] = wtm[k * 512 + tid];
    }
    if (tid < 128) hbuf[tid] = 0.0f;
    float c = 0.0f;
    __syncthreads();

    #pragma unroll
    for (int t = 0; t < 32; t++) {
        if (t < len) {     // uniform across block
            float acc = greg[t];
            #pragma unroll
            for (int k = 0; k < 128; k += 4) {
                float4 h4 = *(const float4*)(hbuf + k);
                acc += wreg[k] * h4.x + wreg[k + 1] * h4.y + wreg[k + 2] * h4.z + wreg[k + 3] * h4.w;
            }
            gates[tid] = acc;
            __syncthreads();
            if (tid < 128) {
                float gi = gates[tid];
                float gf = gates[128 + tid];
                float go = gates[256 + tid];
                float gg = gates[384 + tid];
                c = sigmoid_f(gf) * c + sigmoid_f(gi) * tanh_f(gg);
                float hn = sigmoid_f(go) * tanh_f(c);
                hbuf[tid] = hn;
                int s = dir ? (len - 1 - t) : t;
                int row = r0 + s;
                int w = d - 2 * row;
                if ((unsigned)w < 32u)
                    comb[((b * 32 + row) * 32 + w) * 256 + dir * 128 + tid] = hn;
            }
            __syncthreads();
        }
    }
}

// out[b][o][r][w] = sum_c comb[b][r][w][c] * ow[o][c] + ob[o]
// M = 32768 cells, N = 768, K = 256
__global__ __launch_bounds__(256, 3) void outproj(
    const float* __restrict__ comb,   // [32768][256]
    const float* __restrict__ ow,     // [768][256]
    const float* __restrict__ ob,     // [768]
    float* __restrict__ out)          // [32][768][1024]
{
    __shared__ __align__(16) float un_s[64 * 64];    // [k][cell]
    __shared__ __align__(16) float w_s[64 * 128];    // [k][o]

    const int tid = threadIdx.x;
    const int m0 = blockIdx.x * 64;    // cell base
    const int o0 = blockIdx.y * 128;   // output-channel base

    const int cg = tid & 15;           // cell group: cells cg*4 .. cg*4+3
    const int og = tid >> 4;           // o group: o og*8 .. og*8+7

    const int lc = tid & 15;           // staging: k4 = lc*4
    const int sc = tid >> 4;           // staging: row stepper

    float acc[4][8];
    #pragma unroll
    for (int m = 0; m < 4; m++)
        #pragma unroll
        for (int n = 0; n < 8; n++) acc[m][n] = 0.0f;

    for (int kt = 0; kt < 256; kt += 64) {
        __syncthreads();
        // stage un: 64 cells x 64 k, transposed to [k][cell]
        for (int cc = sc; cc < 64; cc += 16) {
            float4 v = *(const float4*)(comb + (m0 + cc) * 256 + kt + lc * 4);
            un_s[(lc * 4 + 0) * 64 + cc] = v.x;
            un_s[(lc * 4 + 1) * 64 + cc] = v.y;
            un_s[(lc * 4 + 2) * 64 + cc] = v.z;
            un_s[(lc * 4 + 3) * 64 + cc] = v.w;
        }
        // stage w: 128 o x 64 k, transposed to [k][o]
        for (int oo = sc; oo < 128; oo += 16) {
            float4 v = *(const float4*)(ow + (o0 + oo) * 256 + kt + lc * 4);
            w_s[(lc * 4 + 0) * 128 + oo] = v.x;
            w_s[(lc * 4 + 1) * 128 + oo] = v.y;
            w_s[(lc * 4 + 2) * 128 + oo] = v.z;
            w_s[(lc * 4 + 3) * 128 + oo] = v.w;
        }
        __syncthreads();

        #pragma unroll 4
        for (int k = 0; k < 64; k++) {
            float u[4], wv[8];
            *(float4*)u        = *(const float4*)(un_s + k * 64 + cg * 4);
            *(float4*)wv       = *(const float4*)(w_s + k * 128 + og * 8);
            *(float4*)(wv + 4) = *(const float4*)(w_s + k * 128 + og * 8 + 4);
            #pragma unroll
            for (int m = 0; m < 4; m++)
                #pragma unroll
                for (int n = 0; n < 8; n++)
                    acc[m][n] += u[m] * wv[n];
        }
    }

    const int bidx = m0 >> 10;          // batch
    const int rw   = m0 & 1023;         // (r,w) linear base
    #pragma unroll
    for (int n = 0; n < 8; n++) {
        int o = o0 + og * 8 + n;
        float bo = ob[o];
        float4 v;
        v.x = acc[0][n] + bo;
        v.y = acc[1][n] + bo;
        v.z = acc[2][n] + bo;
        v.w = acc[3][n] + bo;
        *(float4*)(out + (bidx * 768 + o) * 1024 + rw + cg * 4) = v;
    }
}

extern "C" void kernel_launch(void* const* d_in, const int* in_sizes, int n_in,
                              void* d_out, int out_size, void* d_ws, size_t ws_size,
                              hipStream_t stream) {
    const float* x      = (const float*)d_in[0];
    const float* ipw    = (const float*)d_in[1];
    const float* ipb    = (const float*)d_in[2];
    const float* fwd_Wi = (const float*)d_in[3];
    const float* fwd_Wh = (const float*)d_in[4];
    const float* fwd_b  = (const float*)d_in[5];
    const float* bwd_Wi = (const float*)d_in[6];
    const float* bwd_Wh = (const float*)d_in[7];
    const float* bwd_b  = (const float*)d_in[8];
    const float* out_w  = (const float*)d_in[9];
    const float* out_b  = (const float*)d_in[10];

    float* ws   = (float*)d_ws;
    float* wt   = ws;
    float* comb = ws + WT_FLOATS;
    float* out  = (float*)d_out;

    hipLaunchKernelGGL(transpose_w, dim3(256, 4), dim3(256), 0, stream,
                       fwd_Wi, fwd_Wh, bwd_Wi, bwd_Wh, wt);

    hipLaunchKernelGGL(lstm_diag, dim3(NSEQ), dim3(512), 0, stream,
                       x, ipw, ipb, fwd_b, bwd_b, wt, comb);

    hipLaunchKernelGGL(outproj, dim3(512, 6), dim3(256), 0, stream,
                       comb, out_w, out_b, out);
}

// Round 6
// 510.587 us; speedup vs baseline: 2.7059x; 2.7059x over previous
//
#include <hip/hip_runtime.h>
#include <hip/hip_bf16.h>

// Problem constants
#define Bb   32
#define Hh   32
#define Ww   32
#define SW   63           // W+H-1
#define DD   94           // H+SW-1

typedef __attribute__((ext_vector_type(8))) short  s8v;    // 8 bf16 (4 VGPRs)
typedef __attribute__((ext_vector_type(4))) float  f32x4;

// ws layout (bytes):
//   [0,      256K) : wip bf16 [2 dirs][128 k][512 g']   (g' = 4*ch + type, type: 0=i,1=f,2=o,3=g)
//   [256K,   512K) : whp bf16 [2 dirs][128 k][512 g']
//   [512K,   516K) : biasp f32 [2 dirs][512 g']
//   [1M,     33M)  : comb f32 [32 b][32 r][32 w][256 ch] (0..127 fwd h, 128..255 bwd h)

__device__ __forceinline__ float sigmoid_f(float v) {
    return 1.0f / (1.0f + __expf(-v));
}
__device__ __forceinline__ float tanh_f(float v) {
    float e = __expf(2.0f * v);
    return 1.0f - 2.0f / (e + 1.0f);
}
__device__ __forceinline__ unsigned short f2bf(float f) {
    unsigned int u = __builtin_bit_cast(unsigned int, f);
    unsigned int r = (u + 0x7fffu + ((u >> 16) & 1u)) >> 16;
    return (unsigned short)r;
}

// ---- prep: W[512][128] f32 -> Wt'[128][512] bf16 with permuted gate cols ----
__global__ void prep_w(const float* __restrict__ fwi, const float* __restrict__ fwh,
                       const float* __restrict__ bwi, const float* __restrict__ bwh,
                       unsigned short* __restrict__ wip, unsigned short* __restrict__ whp) {
    int m = blockIdx.y;
    const float* src = (m == 0) ? fwi : (m == 1) ? fwh : (m == 2) ? bwi : bwh;
    unsigned short* dst = (m == 0) ? wip : (m == 1) ? whp : (m == 2) ? (wip + 65536) : (whp + 65536);
    int idx = blockIdx.x * 256 + threadIdx.x;   // j*128 + k
    int j = idx >> 7;          // original gate row: t*128 + ch
    int k = idx & 127;
    int t  = j >> 7;
    int ch = j & 127;
    int gp = (ch << 2) + t;    // permuted gate index
    dst[k * 512 + gp] = f2bf(src[idx]);
}

__global__ void prep_b(const float* __restrict__ fwd_b, const float* __restrict__ bwd_b,
                       float* __restrict__ biasp) {
    int tid = threadIdx.x;     // 0..1023
    int dir = tid >> 9;
    int gp  = tid & 511;
    int ch  = gp >> 2;
    int t   = gp & 3;
    const float* src = dir ? bwd_b : fwd_b;
    biasp[dir * 512 + gp] = src[t * 128 + ch];
}

// ---- MFMA diagonal LSTM: one block per (d, dir); M = 32 batches ----
__global__ __launch_bounds__(512, 1) void lstm_mfma(
    const float* __restrict__ x,       // (32,3,32,32)
    const float* __restrict__ ipw,     // (128,3)
    const float* __restrict__ ipb,     // (128)
    const unsigned short* __restrict__ wip,   // [2][128][512] bf16
    const unsigned short* __restrict__ whp,   // [2][128][512] bf16
    const float* __restrict__ biasp,   // [2][512]
    float* __restrict__ comb)          // [32][32][32][256]
{
    __shared__ unsigned short h_lds[32 * 128];   // 8KB  (bf16, XOR-swizzled)
    __shared__ unsigned short xp_lds[32 * 128];  // 8KB  (bf16, XOR-swizzled)
    __shared__ float gsl[8 * 16 * 64];           // 32KB  per-wave gate slices
    __shared__ float ipw_s[128 * 3];
    __shared__ float ipb_s[128];

    const int tid  = threadIdx.x;
    const int wv   = tid >> 6;          // wave 0..7: owns g' in [64*wv, 64*wv+64)
    const int lane = tid & 63;
    const int g16  = lane >> 4;         // 0..3
    const int cl   = lane & 15;         // 0..15
    const int chl  = cl >> 2;           // 0..3
    const int tt   = cl & 3;            // 0..3 (gate-type slot of this lane's item)

    const int d   = blockIdx.x >> 1;
    const int dir = blockIdx.x & 1;

    const int r0   = max(0, d - (SW - 1));
    const int rend = min(Hh - 1, d);
    const int len  = rend - r0 + 1;

    const float inv255 = 1.0f / 255.0f;

    // stage ipw/ipb
    if (tid < 384) ipw_s[tid] = ipw[tid];
    else if (tid < 512) ipb_s[tid - 384] = ipb[tid - 384];

    // zero h
    #pragma unroll
    for (int j = 0; j < 8; j++) h_lds[tid + 512 * j] = 0;

    // ---- B-fragments (Wh', Wi') in VGPRs: [nt][kt], 8 bf16 each ----
    const unsigned short* whd = whp + dir * 65536;
    const unsigned short* wid = wip + dir * 65536;
    s8v whB[4][4], wiB[4][4];
    #pragma unroll
    for (int nt = 0; nt < 4; nt++) {
        int gp = wv * 64 + nt * 16 + cl;
        #pragma unroll
        for (int kt = 0; kt < 4; kt++) {
            #pragma unroll
            for (int j = 0; j < 8; j++) {
                int k = kt * 32 + g16 * 8 + j;
                whB[nt][kt][j] = (short)whd[k * 512 + gp];
                wiB[nt][kt][j] = (short)wid[k * 512 + gp];
            }
        }
    }
    float biasf[4];
    #pragma unroll
    for (int nt = 0; nt < 4; nt++) biasf[nt] = biasp[dir * 512 + wv * 64 + nt * 16 + cl];

    __syncthreads();   // ipw_s ready

    // ---- prologue: xp(0) ----
    {
        int s0 = dir ? (len - 1) : 0;
        int row0 = r0 + s0;
        int w0 = d - 2 * row0;
        bool valid0 = ((unsigned)w0 < 32u);
        #pragma unroll
        for (int mt = 0; mt < 2; mt++) {
            int seq = mt * 16 + g16 * 4 + tt;
            float xv0 = 0, xv1 = 0, xv2 = 0;
            if (valid0) {
                const float* xb = x + ((seq * 3) * 32 + row0) * 32 + w0;
                xv0 = xb[0]; xv1 = xb[1024]; xv2 = xb[2048];
            }
            #pragma unroll
            for (int nt = 0; nt < 4; nt++) {
                int ch = wv * 16 + nt * 4 + chl;
                float xpf = 0.0f;
                if (valid0)
                    xpf = ipb_s[ch] + inv255 * (xv0 * ipw_s[ch * 3] + xv1 * ipw_s[ch * 3 + 1] + xv2 * ipw_s[ch * 3 + 2]);
                int idx = (seq * 128 + ch) ^ ((seq & 7) << 3);
                xp_lds[idx] = f2bf(xpf);
            }
        }
    }
    __syncthreads();   // h(=0), xp(0) visible

    float cst[2][4];
    #pragma unroll
    for (int mt = 0; mt < 2; mt++)
        #pragma unroll
        for (int nt = 0; nt < 4; nt++) cst[mt][nt] = 0.0f;

    for (int t = 0; t < len; t++) {
        int s   = dir ? (len - 1 - t) : t;
        int row = r0 + s;
        int w   = d - 2 * row;
        bool valid = ((unsigned)w < 32u);

        // next-step cell
        int s2 = dir ? (len - 2 - t) : (t + 1);
        int row2 = r0 + s2;
        int w2 = d - 2 * row2;
        bool have2 = (t + 1 < len);
        bool valid2 = have2 && ((unsigned)w2 < 32u);

        // ---- MFMA phase: gates = bias + h@Wh'T + xp@Wi'T ----
        f32x4 acc[2][4];
        #pragma unroll
        for (int mt = 0; mt < 2; mt++)
            #pragma unroll
            for (int nt = 0; nt < 4; nt++) {
                f32x4 b4 = {biasf[nt], biasf[nt], biasf[nt], biasf[nt]};
                acc[mt][nt] = b4;
            }
        #pragma unroll
        for (int kt = 0; kt < 4; kt++) {
            s8v ha[2], xa[2];
            #pragma unroll
            for (int mt = 0; mt < 2; mt++) {
                int seqA = mt * 16 + cl;
                int idx = (seqA * 128 + kt * 32 + g16 * 8) ^ ((seqA & 7) << 3);
                ha[mt] = *reinterpret_cast<const s8v*>(&h_lds[idx]);
                xa[mt] = *reinterpret_cast<const s8v*>(&xp_lds[idx]);
            }
            #pragma unroll
            for (int mt = 0; mt < 2; mt++)
                #pragma unroll
                for (int nt = 0; nt < 4; nt++) {
                    acc[mt][nt] = __builtin_amdgcn_mfma_f32_16x16x32_bf16(ha[mt], whB[nt][kt], acc[mt][nt], 0, 0, 0);
                    acc[mt][nt] = __builtin_amdgcn_mfma_f32_16x16x32_bf16(xa[mt], wiB[nt][kt], acc[mt][nt], 0, 0, 0);
                }
        }

        // ---- pointwise per mt (wave-local gate exchange through gsl slice) ----
        unsigned short hq[2][4], xq[2][4];
        #pragma unroll
        for (int mt = 0; mt < 2; mt++) {
            // write this wave's gate slice [16 seq_local][64 g'_local]
            #pragma unroll
            for (int nt = 0; nt < 4; nt++)
                #pragma unroll
                for (int r = 0; r < 4; r++)
                    gsl[(wv * 16 + g16 * 4 + r) * 64 + nt * 16 + cl] = acc[mt][nt][r];
            asm volatile("s_waitcnt lgkmcnt(0)" ::: "memory");

            int seq = mt * 16 + g16 * 4 + tt;
            // x loads for xp(t+1)
            float xv0 = 0, xv1 = 0, xv2 = 0;
            if (valid2) {
                const float* xb = x + ((seq * 3) * 32 + row2) * 32 + w2;
                xv0 = xb[0]; xv1 = xb[1024]; xv2 = xb[2048];
            }
            #pragma unroll
            for (int nt = 0; nt < 4; nt++) {
                const f32x4 gv = *reinterpret_cast<const f32x4*>(
                    &gsl[(wv * 16 + g16 * 4 + tt) * 64 + nt * 16 + chl * 4]);
                float gi = gv[0], gf = gv[1], go = gv[2], gg = gv[3];
                float c = sigmoid_f(gf) * cst[mt][nt] + sigmoid_f(gi) * tanh_f(gg);
                cst[mt][nt] = c;
                float hn = sigmoid_f(go) * tanh_f(c);
                hq[mt][nt] = f2bf(hn);

                int ch = wv * 16 + nt * 4 + chl;
                float xpf = 0.0f;
                if (valid2)
                    xpf = ipb_s[ch] + inv255 * (xv0 * ipw_s[ch * 3] + xv1 * ipw_s[ch * 3 + 1] + xv2 * ipw_s[ch * 3 + 2]);
                xq[mt][nt] = f2bf(xpf);

                if (valid)
                    comb[((seq * 32 + row) * 32 + w) * 256 + dir * 128 + ch] = hn;
            }
        }

        __syncthreads();   // all A-frag reads of h(t-1)/xp(t) done

        #pragma unroll
        for (int mt = 0; mt < 2; mt++) {
            int seq = mt * 16 + g16 * 4 + tt;
            #pragma unroll
            for (int nt = 0; nt < 4; nt++) {
                int ch = wv * 16 + nt * 4 + chl;
                int idx = (seq * 128 + ch) ^ ((seq & 7) << 3);
                h_lds[idx] = hq[mt][nt];
                if (have2) xp_lds[idx] = xq[mt][nt];
            }
        }

        __syncthreads();   // h(t), xp(t+1) visible
    }
}

// out[b][o][r][w] = sum_c comb[b][r][w][c] * ow[o][c] + ob[o]
// M = 32768 cells, N = 768, K = 256   (unchanged from round 4 — known good)
__global__ __launch_bounds__(256, 3) void outproj(
    const float* __restrict__ comb,   // [32768][256]
    const float* __restrict__ ow,     // [768][256]
    const float* __restrict__ ob,     // [768]
    float* __restrict__ out)          // [32][768][1024]
{
    __shared__ __align__(16) float un_s[64 * 64];    // [k][cell]
    __shared__ __align__(16) float w_s[64 * 128];    // [k][o]

    const int tid = threadIdx.x;
    const int m0 = blockIdx.x * 64;    // cell base
    const int o0 = blockIdx.y * 128;   // output-channel base

    const int cg = tid & 15;
    const int og = tid >> 4;

    const int lc = tid & 15;
    const int sc = tid >> 4;

    float acc[4][8];
    #pragma unroll
    for (int m = 0; m < 4; m++)
        #pragma unroll
        for (int n = 0; n < 8; n++) acc[m][n] = 0.0f;

    for (int kt = 0; kt < 256; kt += 64) {
        __syncthreads();
        for (int cc = sc; cc < 64; cc += 16) {
            float4 v = *(const float4*)(comb + (m0 + cc) * 256 + kt + lc * 4);
            un_s[(lc * 4 + 0) * 64 + cc] = v.x;
            un_s[(lc * 4 + 1) * 64 + cc] = v.y;
            un_s[(lc * 4 + 2) * 64 + cc] = v.z;
            un_s[(lc * 4 + 3) * 64 + cc] = v.w;
        }
        for (int oo = sc; oo < 128; oo += 16) {
            float4 v = *(const float4*)(ow + (o0 + oo) * 256 + kt + lc * 4);
            w_s[(lc * 4 + 0) * 128 + oo] = v.x;
            w_s[(lc * 4 + 1) * 128 + oo] = v.y;
            w_s[(lc * 4 + 2) * 128 + oo] = v.z;
            w_s[(lc * 4 + 3) * 128 + oo] = v.w;
        }
        __syncthreads();

        #pragma unroll 4
        for (int k = 0; k < 64; k++) {
            float u[4], wvv[8];
            *(float4*)u         = *(const float4*)(un_s + k * 64 + cg * 4);
            *(float4*)wvv       = *(const float4*)(w_s + k * 128 + og * 8);
            *(float4*)(wvv + 4) = *(const float4*)(w_s + k * 128 + og * 8 + 4);
            #pragma unroll
            for (int m = 0; m < 4; m++)
                #pragma unroll
                for (int n = 0; n < 8; n++)
                    acc[m][n] += u[m] * wvv[n];
        }
    }

    const int bidx = m0 >> 10;
    const int rw   = m0 & 1023;
    #pragma unroll
    for (int n = 0; n < 8; n++) {
        int o = o0 + og * 8 + n;
        float bo = ob[o];
        float4 v;
        v.x = acc[0][n] + bo;
        v.y = acc[1][n] + bo;
        v.z = acc[2][n] + bo;
        v.w = acc[3][n] + bo;
        *(float4*)(out + (bidx * 768 + o) * 1024 + rw + cg * 4) = v;
    }
}

extern "C" void kernel_launch(void* const* d_in, const int* in_sizes, int n_in,
                              void* d_out, int out_size, void* d_ws, size_t ws_size,
                              hipStream_t stream) {
    const float* x      = (const float*)d_in[0];
    const float* ipw    = (const float*)d_in[1];
    const float* ipb    = (const float*)d_in[2];
    const float* fwd_Wi = (const float*)d_in[3];
    const float* fwd_Wh = (const float*)d_in[4];
    const float* fwd_b  = (const float*)d_in[5];
    const float* bwd_Wi = (const float*)d_in[6];
    const float* bwd_Wh = (const float*)d_in[7];
    const float* bwd_b  = (const float*)d_in[8];
    const float* out_w  = (const float*)d_in[9];
    const float* out_b  = (const float*)d_in[10];

    unsigned short* wip   = (unsigned short*)d_ws;                       // 256KB
    unsigned short* whp   = wip + 2 * 65536;                             // 256KB
    float*          biasp = (float*)(whp + 2 * 65536);                   // 4KB
    float*          comb  = (float*)((char*)d_ws + (1 << 20));           // 32MB
    float*          out   = (float*)d_out;

    hipLaunchKernelGGL(prep_w, dim3(256, 4), dim3(256), 0, stream,
                       fwd_Wi, fwd_Wh, bwd_Wi, bwd_Wh, wip, whp);
    hipLaunchKernelGGL(prep_b, dim3(1), dim3(1024), 0, stream,
                       fwd_b, bwd_b, biasp);

    hipLaunchKernelGGL(lstm_mfma, dim3(DD * 2), dim3(512), 0, stream,
                       x, ipw, ipb, wip, whp, biasp, comb);

    hipLaunchKernelGGL(outproj, dim3(512, 6), dim3(256), 0, stream,
                       comb, out_w, out_b, out);
}

// Round 8
// 320.607 us; speedup vs baseline: 4.3092x; 1.5926x over previous
//
#include <hip/hip_runtime.h>

// Problem constants
#define Hh 32
#define Ww 32
#define SW 63           // W+H-1
#define DD 94           // H+SW-1

typedef __attribute__((ext_vector_type(8))) short  s8v;    // 8 bf16 (4 VGPRs)
typedef __attribute__((ext_vector_type(4))) float  f32x4;

// ws layout (bytes):
//   [0,    256K) : whf bf16  [2 dirs][8 wv][4 nt][4 kt][64 lane][8]  (frag-ordered Wh')
//   [256K, 512K) : wif bf16  same layout (Wi')
//   [512K, 516K) : biasp f32 [2 dirs][512 g']    g' = 4*ch + type (0=i,1=f,2=o,3=g)
//   [768K,1152K) : owb bf16  [768][256]
//   [2M,   18M)  : comb bf16 [32 b][32 r][32 w][256 ch] (0..127 fwd h, 128..255 bwd)

__device__ __forceinline__ float sigmoid_f(float v) {
    return 1.0f / (1.0f + __expf(-v));
}
__device__ __forceinline__ float tanh_f(float v) {
    float e = __expf(2.0f * v);
    return 1.0f - 2.0f / (e + 1.0f);
}
__device__ __forceinline__ unsigned short f2bf(float f) {
    unsigned int u = __builtin_bit_cast(unsigned int, f);
    unsigned int r = (u + 0x7fffu + ((u >> 16) & 1u)) >> 16;
    return (unsigned short)r;
}

// ---- prep: W[512][128] f32 -> per-wave MFMA fragment order, bf16 ----
// frag value (dir,wv,nt,kt,lane,j) = W'[k = kt*32+(lane>>4)*8+j][gp = wv*64+nt*16+(lane&15)]
// where W'[k][gp] = W[(gp&3)*128 + (gp>>2)][k]
__global__ void prep_wf(const float* __restrict__ fwi, const float* __restrict__ fwh,
                        const float* __restrict__ bwi, const float* __restrict__ bwh,
                        unsigned short* __restrict__ wif, unsigned short* __restrict__ whf) {
    int m = blockIdx.y;   // 0=fwd Wi, 1=fwd Wh, 2=bwd Wi, 3=bwd Wh
    const float* src = (m == 0) ? fwi : (m == 1) ? fwh : (m == 2) ? bwi : bwh;
    unsigned short* dst = (m & 1) ? whf : wif;
    int dir = m >> 1;

    int t = blockIdx.x * 256 + threadIdx.x;   // 0..16383
    int lane = t & 63;
    int kt   = (t >> 6) & 3;
    int nt   = (t >> 8) & 3;
    int wv   = (t >> 10) & 7;

    int gp = wv * 64 + nt * 16 + (lane & 15);
    int ch = gp >> 2, ty = gp & 3;
    int kbase = kt * 32 + (lane >> 4) * 8;
    const float* srow = src + (ty * 128 + ch) * 128 + kbase;

    s8v v;
    #pragma unroll
    for (int j = 0; j < 8; j++) v[j] = (short)f2bf(srow[j]);
    int off = dir * 65536 + ((wv * 4 + nt) * 4 + kt) * 512 + lane * 8;
    *reinterpret_cast<s8v*>(dst + off) = v;
}

__global__ void prep_b(const float* __restrict__ fwd_b, const float* __restrict__ bwd_b,
                       float* __restrict__ biasp) {
    int tid = threadIdx.x;     // 0..1023
    int dir = tid >> 9;
    int gp  = tid & 511;
    int ch  = gp >> 2;
    int ty  = gp & 3;
    const float* src = dir ? bwd_b : fwd_b;
    biasp[dir * 512 + gp] = src[ty * 128 + ch];
}

__global__ void prep_ow(const float* __restrict__ ow, unsigned short* __restrict__ owb) {
    int i = blockIdx.x * 1024 + threadIdx.x;   // 0..196607
    owb[i] = f2bf(ow[i]);
}

// ---- MFMA diagonal LSTM: one block per (d, dir); M = 32 batches ----
// Operand order: A = weights (m = g'), B = h/xp (n = seq/batch).
// Lane (g16 = lane>>4, cl = lane&15) ends with acc[mt][nt][r] =
//   gate type r for cell (seq = mt*16+cl, ch = wv*16 + nt*4 + g16) -> pointwise in-register.
__global__ __launch_bounds__(512, 2) void lstm_mfma(
    const float* __restrict__ x,       // (32,3,32,32)
    const float* __restrict__ ipw,     // (128,3)
    const float* __restrict__ ipb,     // (128)
    const unsigned short* __restrict__ whf,
    const unsigned short* __restrict__ wif,
    const float* __restrict__ biasp,   // [2][512]
    unsigned short* __restrict__ comb) // [32][32][32][256] bf16
{
    __shared__ unsigned short h_lds[2][32 * 128];   // 2 x 8KB, XOR-swizzled
    __shared__ unsigned short xp_lds[2][32 * 128];  // 2 x 8KB
    __shared__ float ipw_s[384];
    __shared__ float ipb_s[128];

    const int tid  = threadIdx.x;
    const int wv   = tid >> 6;
    const int lane = tid & 63;
    const int g16  = lane >> 4;
    const int cl   = lane & 15;
    const int swz  = (cl & 7) << 3;    // seq&7 == cl&7 for seq = mt*16+cl

    const int d   = blockIdx.x >> 1;
    const int dir = blockIdx.x & 1;
    const int r0   = max(0, d - (SW - 1));
    const int rend = min(Hh - 1, d);
    const int len  = rend - r0 + 1;
    const float inv255 = 1.0f / 255.0f;

    // ---- weight fragments (coalesced 16B loads) ----
    s8v whB[4][4], wiB[4][4];
    {
        const unsigned short* whd = whf + dir * 65536;
        const unsigned short* wid = wif + dir * 65536;
        #pragma unroll
        for (int nt = 0; nt < 4; nt++)
            #pragma unroll
            for (int kt = 0; kt < 4; kt++) {
                int off = ((wv * 4 + nt) * 4 + kt) * 512 + lane * 8;
                whB[nt][kt] = *reinterpret_cast<const s8v*>(whd + off);
                wiB[nt][kt] = *reinterpret_cast<const s8v*>(wid + off);
            }
    }
    f32x4 bias4[4];
    #pragma unroll
    for (int nt = 0; nt < 4; nt++)
        bias4[nt] = *reinterpret_cast<const f32x4*>(biasp + dir * 512 + wv * 64 + nt * 16 + g16 * 4);

    if (tid < 384) ipw_s[tid] = ipw[tid];
    else if (tid < 512) ipb_s[tid - 384] = ipb[tid - 384];

    {   // zero h buffer 0 (512 thr x 4 dwords = 4096 ushorts)
        unsigned int* hz = reinterpret_cast<unsigned int*>(&h_lds[0][0]);
        #pragma unroll
        for (int j = 0; j < 4; j++) hz[tid * 4 + j] = 0u;
    }
    __syncthreads();   // ipw_s/ipb_s + h zero visible

    // ---- prologue: xp(0) ----
    {
        int s0 = dir ? (len - 1) : 0;
        int row0 = r0 + s0;
        int w0 = d - 2 * row0;
        bool valid0 = ((unsigned)w0 < 32u);
        #pragma unroll
        for (int mt = 0; mt < 2; mt++) {
            int seq = mt * 16 + cl;
            float xv0 = 0, xv1 = 0, xv2 = 0;
            if (valid0) {
                const float* xb = x + seq * 3072 + row0 * 32 + w0;
                xv0 = xb[0]; xv1 = xb[1024]; xv2 = xb[2048];
            }
            #pragma unroll
            for (int nt = 0; nt < 4; nt++) {
                int ch = wv * 16 + nt * 4 + g16;
                float xpf = 0.0f;
                if (valid0)
                    xpf = ipb_s[ch] + inv255 * (xv0 * ipw_s[ch * 3] + xv1 * ipw_s[ch * 3 + 1] + xv2 * ipw_s[ch * 3 + 2]);
                xp_lds[0][(seq * 128 + ch) ^ swz] = f2bf(xpf);
            }
        }
    }
    __syncthreads();   // xp(0) visible

    float cst[2][4];
    #pragma unroll
    for (int mt = 0; mt < 2; mt++)
        #pragma unroll
        for (int nt = 0; nt < 4; nt++) cst[mt][nt] = 0.0f;

    int cur = 0;
    for (int t = 0; t < len; t++) {
        int s   = dir ? (len - 1 - t) : t;
        int row = r0 + s;
        int w   = d - 2 * row;
        bool valid = ((unsigned)w < 32u);

        int s2 = dir ? (len - 2 - t) : (t + 1);
        bool have2 = (t + 1 < len);
        int row2 = r0 + s2;
        int w2 = d - 2 * row2;
        bool valid2 = have2 && ((unsigned)w2 < 32u);

        // ---- MFMA: gates[g'][seq] = bias + Wh'^T h + Wi'^T xp ----
        f32x4 acc[2][4];
        #pragma unroll
        for (int mt = 0; mt < 2; mt++)
            #pragma unroll
            for (int nt = 0; nt < 4; nt++) acc[mt][nt] = bias4[nt];

        #pragma unroll
        for (int kt = 0; kt < 4; kt++) {
            s8v hfr[2], xfr[2];
            #pragma unroll
            for (int mt = 0; mt < 2; mt++) {
                int idx = ((mt * 16 + cl) * 128 + kt * 32 + g16 * 8) ^ swz;
                hfr[mt] = *reinterpret_cast<const s8v*>(&h_lds[cur][idx]);
                xfr[mt] = *reinterpret_cast<const s8v*>(&xp_lds[cur][idx]);
            }
            #pragma unroll
            for (int mt = 0; mt < 2; mt++)
                #pragma unroll
                for (int nt = 0; nt < 4; nt++) {
                    acc[mt][nt] = __builtin_amdgcn_mfma_f32_16x16x32_bf16(whB[nt][kt], hfr[mt], acc[mt][nt], 0, 0, 0);
                    acc[mt][nt] = __builtin_amdgcn_mfma_f32_16x16x32_bf16(wiB[nt][kt], xfr[mt], acc[mt][nt], 0, 0, 0);
                }
        }

        // ---- pointwise fully in-register; write h(t), xp(t+1), comb ----
        int nxt = cur ^ 1;
        #pragma unroll
        for (int mt = 0; mt < 2; mt++) {
            int seq = mt * 16 + cl;
            float xv0 = 0, xv1 = 0, xv2 = 0;
            if (valid2) {
                const float* xb = x + seq * 3072 + row2 * 32 + w2;
                xv0 = xb[0]; xv1 = xb[1024]; xv2 = xb[2048];
            }
            #pragma unroll
            for (int nt = 0; nt < 4; nt++) {
                int ch = wv * 16 + nt * 4 + g16;
                float gi = acc[mt][nt][0];
                float gf = acc[mt][nt][1];
                float go = acc[mt][nt][2];
                float gg = acc[mt][nt][3];
                float c = sigmoid_f(gf) * cst[mt][nt] + sigmoid_f(gi) * tanh_f(gg);
                cst[mt][nt] = c;
                float hn = sigmoid_f(go) * tanh_f(c);
                unsigned short hq = f2bf(hn);

                int idx = (seq * 128 + ch) ^ swz;
                h_lds[nxt][idx] = hq;
                if (valid)
                    comb[((seq * 32 + row) * 32 + w) * 256 + dir * 128 + ch] = hq;
                if (have2) {
                    float xpf = 0.0f;
                    if (valid2)
                        xpf = ipb_s[ch] + inv255 * (xv0 * ipw_s[ch * 3] + xv1 * ipw_s[ch * 3 + 1] + xv2 * ipw_s[ch * 3 + 2]);
                    xp_lds[nxt][idx] = f2bf(xpf);
                }
            }
        }
        __syncthreads();   // h(t)/xp(t+1) visible; reads of [cur] all done
        cur = nxt;
    }
}

// ---- out projection: bf16 MFMA GEMM. M=32768 cells, N=768 o, K=256 ----
// Block 256 thr = 4 waves (2 o-halves x 2 cell-halves); tile 128 o x 128 cells.
// A = owb (m = o), B = comb (n = cell). No LDS: frags straight from global.
__global__ __launch_bounds__(256) void outproj_mfma(
    const unsigned short* __restrict__ comb,   // [32768][256] bf16
    const unsigned short* __restrict__ owb,    // [768][256] bf16
    const float* __restrict__ ob,              // [768]
    float* __restrict__ out)                   // [32][768][1024] f32
{
    const int tid  = threadIdx.x;
    const int wave = tid >> 6;
    const int wo   = wave >> 1;       // 0..1
    const int wc   = wave & 1;        // 0..1
    const int lane = tid & 63;
    const int g16  = lane >> 4;
    const int cl   = lane & 15;

    const int o_base = blockIdx.y * 128 + wo * 64;
    const int c_base = blockIdx.x * 128 + wc * 64;

    f32x4 acc[4][4];
    #pragma unroll
    for (int of = 0; of < 4; of++)
        #pragma unroll
        for (int cf = 0; cf < 4; cf++) {
            f32x4 z = {0.f, 0.f, 0.f, 0.f};
            acc[of][cf] = z;
        }

    for (int kt = 0; kt < 8; kt++) {
        int kb = kt * 32 + g16 * 8;
        s8v a[4], b[4];
        #pragma unroll
        for (int of = 0; of < 4; of++)
            a[of] = *reinterpret_cast<const s8v*>(owb + (o_base + of * 16 + cl) * 256 + kb);
        #pragma unroll
        for (int cf = 0; cf < 4; cf++)
            b[cf] = *reinterpret_cast<const s8v*>(comb + (c_base + cf * 16 + cl) * 256 + kb);
        #pragma unroll
        for (int of = 0; of < 4; of++)
            #pragma unroll
            for (int cf = 0; cf < 4; cf++)
                acc[of][cf] = __builtin_amdgcn_mfma_f32_16x16x32_bf16(a[of], b[cf], acc[of][cf], 0, 0, 0);
    }

    #pragma unroll
    for (int of = 0; of < 4; of++) {
        f32x4 obv = *reinterpret_cast<const f32x4*>(ob + o_base + of * 16 + g16 * 4);
        #pragma unroll
        for (int cf = 0; cf < 4; cf++) {
            int cell = c_base + cf * 16 + cl;
            int bi = cell >> 10;
            int rw = cell & 1023;
            #pragma unroll
            for (int r = 0; r < 4; r++) {
                int o = o_base + of * 16 + g16 * 4 + r;
                out[(bi * 768 + o) * 1024 + rw] = acc[of][cf][r] + obv[r];
            }
        }
    }
}

extern "C" void kernel_launch(void* const* d_in, const int* in_sizes, int n_in,
                              void* d_out, int out_size, void* d_ws, size_t ws_size,
                              hipStream_t stream) {
    const float* x      = (const float*)d_in[0];
    const float* ipw    = (const float*)d_in[1];
    const float* ipb    = (const float*)d_in[2];
    const float* fwd_Wi = (const float*)d_in[3];
    const float* fwd_Wh = (const float*)d_in[4];
    const float* fwd_b  = (const float*)d_in[5];
    const float* bwd_Wi = (const float*)d_in[6];
    const float* bwd_Wh = (const float*)d_in[7];
    const float* bwd_b  = (const float*)d_in[8];
    const float* out_w  = (const float*)d_in[9];
    const float* out_b  = (const float*)d_in[10];

    char* ws = (char*)d_ws;
    unsigned short* whf   = (unsigned short*)(ws);                 // 256 KB
    unsigned short* wif   = (unsigned short*)(ws + (256 << 10));   // 256 KB
    float*          biasp = (float*)(ws + (512 << 10));            // 4 KB
    unsigned short* owb   = (unsigned short*)(ws + (768 << 10));   // 384 KB
    unsigned short* comb  = (unsigned short*)(ws + (2 << 20));     // 16 MB
    float*          out   = (float*)d_out;

    hipLaunchKernelGGL(prep_wf, dim3(64, 4), dim3(256), 0, stream,
                       fwd_Wi, fwd_Wh, bwd_Wi, bwd_Wh, wif, whf);
    hipLaunchKernelGGL(prep_b, dim3(1), dim3(1024), 0, stream,
                       fwd_b, bwd_b, biasp);
    hipLaunchKernelGGL(prep_ow, dim3(192), dim3(1024), 0, stream,
                       out_w, owb);

    hipLaunchKernelGGL(lstm_mfma, dim3(DD * 2), dim3(512), 0, stream,
                       x, ipw, ipb, whf, wif, biasp, comb);

    hipLaunchKernelGGL(outproj_mfma, dim3(256, 6), dim3(256), 0, stream,
                       comb, owb, out_b, out);
}